// Round 9
// baseline (21.268 us; speedup 1.0000x reference)
//
#include <hip/hip_runtime.h>
#include <math.h>

#define NB    4
#define NPTS  4096
#define BN    (NB * NPTS)
#define TPB   512                 // 8 waves
#define QPB   64                  // queries per block
#define NBLK  (BN / QPB)          // 256 blocks -> 1 per CU
#define G     32                  // j-groups per block
#define JG    (NPTS / G)          // 128 j per group
#define IT    4                   // queries per thread
#define QCOLS (QPB / IT)          // 16 query-columns
#define NW    (TPB / 64)          // 8 waves
#define NGRP  8                   // level-0 counter groups
#define BPG   (NBLK / NGRP)       // 32 blocks per group
#define PADIDX(i) ((i) + ((i) >> 7))   // +1 float4 pad per 128 entries

__device__ inline float wave_sum(float v) {
#pragma unroll
    for (int o = 32; o > 0; o >>= 1) v += __shfl_xor(v, o);
    return v;
}

// One block = 64 queries of one batch vs ALL 4096 points (staged in LDS).
// t = g_local*16 + qcol; wave w owns groups [4w, 4w+4).
// Finisher: 2-level atomicInc-wrap tree (poison-proof, no init/reset):
//   level 0: 8 counters on separate 128B lines, 32 blocks each;
//   level 1: one counter, 8 arrivals. Winner reduces the 3KB bpart array.
__global__ __launch_bounds__(TPB) void fused_kernel(const float* __restrict__ pc,
                                                    float* __restrict__ bpart,
                                                    unsigned int* __restrict__ cnt0,
                                                    unsigned int* __restrict__ cnt1,
                                                    float* __restrict__ out) {
    __shared__ float4 lpt[NPTS + G];
    __shared__ float  smin[NW][QPB];
    __shared__ float  scen[NW][3];
    __shared__ float  svar[NB], ses[NB];
    __shared__ unsigned int s_flag;

    int b    = blockIdx.x >> 6;        // batch (64 blocks per batch)
    int blkq = blockIdx.x & 63;        // query-block within batch
    int iq0  = blkq * QPB;
    const float* p = pc + (size_t)b * NPTS * 3;
    int t = threadIdx.x;
    int lane = t & 63, w = t >> 6;

    // ---- stage batch (x,y,z,|x|^2) + centroid partials from the same regs ----
    float sx = 0.f, sy = 0.f, sz = 0.f;
    for (int i = t; i < NPTS; i += TPB) {
        float x = p[3*i+0], y = p[3*i+1], z = p[3*i+2];
        lpt[PADIDX(i)] = make_float4(x, y, z, fmaf(x, x, fmaf(y, y, z * z)));
        sx += x; sy += y; sz += z;
    }
    sx = wave_sum(sx); sy = wave_sum(sy); sz = wave_sum(sz);
    if (lane == 0) { scen[w][0] = sx; scen[w][1] = sy; scen[w][2] = sz; }
    __syncthreads();

    // ---- per-thread: 4 queries (prefolded -2x) vs group g's 128 points ----
    int qcol = t & (QCOLS - 1);
    int g    = t >> 4;                 // global group index 0..31
    float ax[IT], ay[IT], az[IT], m[IT];
#pragma unroll
    for (int k = 0; k < IT; ++k) {
        int iq = iq0 + qcol * IT + k;
        float4 q = lpt[PADIDX(iq)];
        ax[k] = -2.f * q.x; ay[k] = -2.f * q.y; az[k] = -2.f * q.z;
        m[k] = 1e30f;
    }
    const float4* gp = &lpt[g * (JG + 1)];

    int gd = blkq >> 1;                // group containing this block's queries
    int wd = blkq >> 3;                // wave owning that group
    if (w == wd) {                     // wave-uniform diagonal branch
        int idl[IT];
#pragma unroll
        for (int k = 0; k < IT; ++k)
            idl[k] = (g == gd) ? (iq0 + qcol * IT + k - gd * JG) : -1;
#pragma unroll 4
        for (int j = 0; j < JG; ++j) {
            float4 q = gp[j];
#pragma unroll
            for (int k = 0; k < IT; ++k) {
                float e = fmaf(ax[k], q.x, fmaf(ay[k], q.y, fmaf(az[k], q.z, q.w)));
                m[k] = fminf(m[k], (j == idl[k]) ? 1e30f : e);
            }
        }
    } else {
#pragma unroll 8
        for (int j = 0; j < JG; j += 2) {      // paired -> v_min3
            float4 q0 = gp[j], q1 = gp[j+1];
#pragma unroll
            for (int k = 0; k < IT; ++k) {
                float e0 = fmaf(ax[k], q0.x, fmaf(ay[k], q0.y, fmaf(az[k], q0.z, q0.w)));
                float e1 = fmaf(ax[k], q1.x, fmaf(ay[k], q1.y, fmaf(az[k], q1.z, q1.w)));
                m[k] = fminf(fminf(m[k], e0), e1);
            }
        }
    }

    // ---- min across the wave's 4 groups (xor 16, 32) ----
#pragma unroll
    for (int k = 0; k < IT; ++k) {
        m[k] = fminf(m[k], __shfl_xor(m[k], 16));
        m[k] = fminf(m[k], __shfl_xor(m[k], 32));
    }
    if (lane < QCOLS) {
#pragma unroll
        for (int k = 0; k < IT; ++k) smin[w][qcol * IT + k] = m[k];
    }
    __syncthreads();

    // ---- wave 0: min across 8 waves, exp, variance terms, block partials ----
    if (t < QPB) {
        float cx = 0.f, cy = 0.f, cz = 0.f;
#pragma unroll
        for (int ww = 0; ww < NW; ++ww) {
            cx += scen[ww][0]; cy += scen[ww][1]; cz += scen[ww][2];
        }
        cx *= (1.f / NPTS); cy *= (1.f / NPTS); cz *= (1.f / NPTS);

        float mm = smin[0][t];
#pragma unroll
        for (int ww = 1; ww < NW; ++ww) mm = fminf(mm, smin[ww][t]);

        int iq = iq0 + t;
        float4 q = lpt[PADIDX(iq)];
        float es = __expf(-5.f * fmaxf(q.w + mm, 0.f));   // clamp commutes with min

        float dx = q.x - cx, dy = q.y - cy, dz = q.z - cz;
        float d2 = fmaf(dx, dx, fmaf(dy, dy, dz * dz));
        float s1 = sqrtf(d2);

        es = wave_sum(es);
        float S1 = wave_sum(s1);
        float S2 = wave_sum(d2);
        if (t == 0) {
            bpart[blockIdx.x * 3 + 0] = S1;
            bpart[blockIdx.x * 3 + 1] = S2;
            bpart[blockIdx.x * 3 + 2] = es;
            __threadfence();                           // release bpart store
            s_flag = 0u;
            // level 0: 32 arrivals on this group's private line.
            // wrap-increment: exactly one arrival observes BPG-2 per call,
            // for ANY initial value (poison-proof, no init/reset).
            unsigned int grp = blockIdx.x >> 5;        // 0..7
            unsigned int o0 = atomicInc(&cnt0[grp * 32], BPG - 1u);
            if (o0 == BPG - 2u) {
                // level 1: 8 arrivals on one line.
                unsigned int o1 = atomicInc(cnt1, NGRP - 1u);
                if (o1 == NGRP - 2u) s_flag = 1u;
            }
        }
    }
    __syncthreads();
    if (s_flag != 1u) return;

    // ---- winner block: reduce 256x3 partials, write scalar ----
    __threadfence();                                   // acquire
    if (t < NBLK) {
        float s1 = bpart[t*3+0], s2 = bpart[t*3+1], e = bpart[t*3+2];
        s1 = wave_sum(s1); s2 = wave_sum(s2); e = wave_sum(e);
        if ((t & 63) == 0) {                           // wave w == batch w
            int bb = t >> 6;
            svar[bb] = (s2 - s1 * s1 * (1.f / NPTS)) * (1.f / (NPTS - 1));
            ses[bb]  = e;
        }
    }
    __syncthreads();
    if (t == 0) {
        float vs = 0.f, et = 0.f;
#pragma unroll
        for (int bb = 0; bb < NB; ++bb) { vs += svar[bb]; et += ses[bb]; }
        out[0] = vs * (1.f / NB) + et * (1.f / BN);
    }
}

extern "C" void kernel_launch(void* const* d_in, const int* in_sizes, int n_in,
                              void* d_out, int out_size, void* d_ws, size_t ws_size,
                              hipStream_t stream) {
    const float* pc = (const float*)d_in[0];
    float* out = (float*)d_out;
    unsigned int* cnt0 = (unsigned int*)d_ws;                  // 8 counters, 128B apart
    unsigned int* cnt1 = (unsigned int*)((char*)d_ws + 1024);  // 1 counter
    float* bpart = (float*)((char*)d_ws + 4096);               // NBLK*3 floats = 3 KB

    fused_kernel<<<NBLK, TPB, 0, stream>>>(pc, bpart, cnt0, cnt1, out);
}

// Round 10
// 18.115 us; speedup vs baseline: 1.1741x; 1.1741x over previous
//
#include <hip/hip_runtime.h>
#include <math.h>

#define NB    4
#define NPTS  4096
#define BN    (NB * NPTS)
#define TPB   512                 // 8 waves
#define QPB   64                  // queries per block
#define NBLK  (BN / QPB)          // 256 blocks -> 1 per CU
#define G     32                  // j-groups per block
#define JG    (NPTS / G)          // 128 j per group
#define IT    4                   // queries per thread
#define QCOLS (QPB / IT)          // 16 query-columns
#define NW    (TPB / 64)          // 8 waves
#define PADIDX(i) ((i) + ((i) >> 7))   // +1 float4 pad per 128 entries

__device__ inline float wave_sum(float v) {
#pragma unroll
    for (int o = 32; o > 0; o >>= 1) v += __shfl_xor(v, o);
    return v;
}

// One block = 64 queries of one batch vs ALL 4096 points (staged in LDS).
// t = g_local*16 + qcol; wave w owns groups [4w, 4w+4).
// Staging: 3 contiguous float4 per thread = 4 points (coalesced), unpack in regs.
// Diagonal wave: paired loop with wave-uniform window test (32/64 pairs masked).
__global__ __launch_bounds__(TPB) void fused_kernel(const float* __restrict__ pc,
                                                    float* __restrict__ bpart) {
    __shared__ float4 lpt[NPTS + G];
    __shared__ float  smin[NW][QPB];
    __shared__ float  scen[NW][3];

    int b    = blockIdx.x >> 6;        // batch (64 blocks per batch)
    int blkq = blockIdx.x & 63;        // query-block within batch
    int iq0  = blkq * QPB;
    const float*  p  = pc + (size_t)b * NPTS * 3;
    const float4* pv = (const float4*)p;   // 3072 float4 per batch
    int t = threadIdx.x;
    int lane = t & 63, w = t >> 6;

    // ---- stage batch: 4 points per thread per half, centroid folded ----
    float sx = 0.f, sy = 0.f, sz = 0.f;
#pragma unroll
    for (int h = 0; h < 2; ++h) {
        int u = h * TPB + t;           // point-quad index 0..1023
        float4 a = pv[3*u+0], d = pv[3*u+1], c = pv[3*u+2];
        int i0 = 4 * u;
        // points: (a.x,a.y,a.z) (a.w,d.x,d.y) (d.z,d.w,c.x) (c.y,c.z,c.w)
        lpt[PADIDX(i0+0)] = make_float4(a.x, a.y, a.z, fmaf(a.x,a.x, fmaf(a.y,a.y, a.z*a.z)));
        lpt[PADIDX(i0+1)] = make_float4(a.w, d.x, d.y, fmaf(a.w,a.w, fmaf(d.x,d.x, d.y*d.y)));
        lpt[PADIDX(i0+2)] = make_float4(d.z, d.w, c.x, fmaf(d.z,d.z, fmaf(d.w,d.w, c.x*c.x)));
        lpt[PADIDX(i0+3)] = make_float4(c.y, c.z, c.w, fmaf(c.y,c.y, fmaf(c.z,c.z, c.w*c.w)));
        sx += a.x + a.w + d.z + c.y;
        sy += a.y + d.x + d.w + c.z;
        sz += a.z + d.y + c.x + c.w;
    }
    sx = wave_sum(sx); sy = wave_sum(sy); sz = wave_sum(sz);
    if (lane == 0) { scen[w][0] = sx; scen[w][1] = sy; scen[w][2] = sz; }
    __syncthreads();

    // ---- per-thread: 4 queries (prefolded -2x) vs group g's 128 points ----
    int qcol = t & (QCOLS - 1);
    int g    = t >> 4;                 // global group index 0..31
    float ax[IT], ay[IT], az[IT], m[IT];
#pragma unroll
    for (int k = 0; k < IT; ++k) {
        int iq = iq0 + qcol * IT + k;
        float4 q = lpt[PADIDX(iq)];
        ax[k] = -2.f * q.x; ay[k] = -2.f * q.y; az[k] = -2.f * q.z;
        m[k] = 1e30f;
    }
    const float4* gp = &lpt[g * (JG + 1)];

    int gd = blkq >> 1;                // group containing this block's queries
    int wd = blkq >> 3;                // wave owning that group
    if (w == wd) {                     // wave containing the diagonal group
        // self window start (aligned 4) for diag-group threads; far away otherwise
        int jd = (g == gd) ? (64 * (blkq & 1) + 4 * qcol) : -1000000;
#pragma unroll 4
        for (int j = 0; j < JG; j += 2) {
            float4 q0 = gp[j], q1 = gp[j+1];
            float e0[IT], e1[IT];
#pragma unroll
            for (int k = 0; k < IT; ++k) {
                e0[k] = fmaf(ax[k], q0.x, fmaf(ay[k], q0.y, fmaf(az[k], q0.z, q0.w)));
                e1[k] = fmaf(ax[k], q1.x, fmaf(ay[k], q1.y, fmaf(az[k], q1.z, q1.w)));
            }
            if (__any((unsigned)(j - jd) < 4u)) {      // wave-uniform: 32 of 64 pairs
#pragma unroll
                for (int k = 0; k < IT; ++k) {
                    float t0 = (j     == jd + k) ? 1e30f : e0[k];
                    float t1 = (j + 1 == jd + k) ? 1e30f : e1[k];
                    m[k] = fminf(m[k], fminf(t0, t1));
                }
            } else {
#pragma unroll
                for (int k = 0; k < IT; ++k)
                    m[k] = fminf(m[k], fminf(e0[k], e1[k]));
            }
        }
    } else {
#pragma unroll 8
        for (int j = 0; j < JG; j += 2) {      // paired -> v_min3
            float4 q0 = gp[j], q1 = gp[j+1];
#pragma unroll
            for (int k = 0; k < IT; ++k) {
                float e0 = fmaf(ax[k], q0.x, fmaf(ay[k], q0.y, fmaf(az[k], q0.z, q0.w)));
                float e1 = fmaf(ax[k], q1.x, fmaf(ay[k], q1.y, fmaf(az[k], q1.z, q1.w)));
                m[k] = fminf(fminf(m[k], e0), e1);
            }
        }
    }

    // ---- min across the wave's 4 groups (xor 16, 32) ----
#pragma unroll
    for (int k = 0; k < IT; ++k) {
        m[k] = fminf(m[k], __shfl_xor(m[k], 16));
        m[k] = fminf(m[k], __shfl_xor(m[k], 32));
    }
    if (lane < QCOLS) {
#pragma unroll
        for (int k = 0; k < IT; ++k) smin[w][qcol * IT + k] = m[k];
    }
    __syncthreads();

    // ---- wave 0: min across 8 waves, exp, variance terms, block partials ----
    if (t < QPB) {
        float cx = 0.f, cy = 0.f, cz = 0.f;
#pragma unroll
        for (int ww = 0; ww < NW; ++ww) {
            cx += scen[ww][0]; cy += scen[ww][1]; cz += scen[ww][2];
        }
        cx *= (1.f / NPTS); cy *= (1.f / NPTS); cz *= (1.f / NPTS);

        float mm = smin[0][t];
#pragma unroll
        for (int ww = 1; ww < NW; ++ww) mm = fminf(mm, smin[ww][t]);

        int iq = iq0 + t;
        float4 q = lpt[PADIDX(iq)];
        float es = __expf(-5.f * fmaxf(q.w + mm, 0.f));   // clamp commutes with min

        float dx = q.x - cx, dy = q.y - cy, dz = q.z - cz;
        float d2 = fmaf(dx, dx, fmaf(dy, dy, dz * dz));
        float s1 = sqrtf(d2);

        es = wave_sum(es);
        float S1 = wave_sum(s1);
        float S2 = wave_sum(d2);
        if (t == 0) {
            bpart[blockIdx.x * 3 + 0] = S1;
            bpart[blockIdx.x * 3 + 1] = S2;
            bpart[blockIdx.x * 3 + 2] = es;
        }
    }
}

// wave w reduces batch w's 64 block-partials; lane0s combine via LDS.
__global__ __launch_bounds__(256) void finish_kernel(const float* __restrict__ bpart,
                                                     float* __restrict__ out) {
    __shared__ float svar[NB], ses[NB];
    int t = threadIdx.x;
    int w = t >> 6;                    // batch
    float s1 = bpart[t*3+0], s2 = bpart[t*3+1], es = bpart[t*3+2];
    s1 = wave_sum(s1); s2 = wave_sum(s2); es = wave_sum(es);
    if ((t & 63) == 0) {
        svar[w] = (s2 - s1 * s1 * (1.f / NPTS)) * (1.f / (NPTS - 1));
        ses[w]  = es;
    }
    __syncthreads();
    if (t == 0) {
        float vs = 0.f, et = 0.f;
#pragma unroll
        for (int bb = 0; bb < NB; ++bb) { vs += svar[bb]; et += ses[bb]; }
        out[0] = vs * (1.f / NB) + et * (1.f / BN);
    }
}

extern "C" void kernel_launch(void* const* d_in, const int* in_sizes, int n_in,
                              void* d_out, int out_size, void* d_ws, size_t ws_size,
                              hipStream_t stream) {
    const float* pc = (const float*)d_in[0];
    float* out   = (float*)d_out;
    float* bpart = (float*)d_ws;       // NBLK*3 floats = 3 KB

    fused_kernel<<<NBLK, TPB, 0, stream>>>(pc, bpart);
    finish_kernel<<<1, 256, 0, stream>>>(bpart, out);
}

// Round 11
// 15.810 us; speedup vs baseline: 1.3452x; 1.1458x over previous
//
#include <hip/hip_runtime.h>
#include <math.h>

#define NB    4
#define NPTS  4096
#define BN    (NB * NPTS)
#define TPB   1024                // 16 waves -> 4 waves/SIMD at 1 block/CU
#define QPB   64                  // queries per block
#define NBLK  (BN / QPB)          // 256 blocks -> 1 per CU
#define G     64                  // j-groups per block
#define JG    (NPTS / G)          // 64 j per group
#define IT    4                   // queries per thread
#define QCOLS (QPB / IT)          // 16 query-columns
#define NW    (TPB / 64)          // 16 waves
#define PADIDX(i) ((i) + ((i) >> 6))   // +1 float4 pad per 64 entries (stride 65)

__device__ inline float wave_sum(float v) {
#pragma unroll
    for (int o = 32; o > 0; o >>= 1) v += __shfl_xor(v, o);
    return v;
}

// One block = 64 queries of one batch vs ALL 4096 points (staged in LDS).
// t = (g, qcol): qcol = t&15, g = t>>4 (64 groups of 64 j). Wave w owns groups
// [4w, 4w+4); stride-65 float4 puts them on disjoint bank quads (broadcast reads).
__global__ __launch_bounds__(TPB) void fused_kernel(const float* __restrict__ pc,
                                                    float* __restrict__ bpart) {
    __shared__ float4 lpt[NPTS + G];
    __shared__ float  smin[NW][QPB];
    __shared__ float  scen[NW][3];

    int b    = blockIdx.x >> 6;        // batch (64 blocks per batch)
    int blkq = blockIdx.x & 63;        // query-block within batch
    int iq0  = blkq * QPB;
    const float* p = pc + (size_t)b * NPTS * 3;
    int t = threadIdx.x;
    int lane = t & 63, w = t >> 6;

    // ---- stage batch (x,y,z,|x|^2) + centroid partials folded ----
    float sx = 0.f, sy = 0.f, sz = 0.f;
#pragma unroll
    for (int i = t; i < NPTS; i += TPB) {
        float x = p[3*i+0], y = p[3*i+1], z = p[3*i+2];
        lpt[PADIDX(i)] = make_float4(x, y, z, fmaf(x, x, fmaf(y, y, z * z)));
        sx += x; sy += y; sz += z;
    }
    sx = wave_sum(sx); sy = wave_sum(sy); sz = wave_sum(sz);
    if (lane == 0) { scen[w][0] = sx; scen[w][1] = sy; scen[w][2] = sz; }
    __syncthreads();

    // ---- per-thread: 4 queries (prefolded -2x) vs group g's 64 points ----
    int qcol = t & (QCOLS - 1);
    int g    = t >> 4;                 // global group index 0..63
    float ax[IT], ay[IT], az[IT], m[IT];
#pragma unroll
    for (int k = 0; k < IT; ++k) {
        int iq = iq0 + qcol * IT + k;
        float4 q = lpt[PADIDX(iq)];
        ax[k] = -2.f * q.x; ay[k] = -2.f * q.y; az[k] = -2.f * q.z;
        m[k] = 1e30f;
    }
    const float4* gp = &lpt[g * (JG + 1)];

    int gd = blkq;                     // group holding this block's queries (JG==QPB)
    int wd = gd >> 2;                  // wave owning that group
    if (w == wd) {                     // wave-uniform diagonal branch
        int idl[IT];
#pragma unroll
        for (int k = 0; k < IT; ++k)
            idl[k] = (g == gd) ? (qcol * IT + k) : -1;
#pragma unroll 4
        for (int j = 0; j < JG; ++j) {
            float4 q = gp[j];
#pragma unroll
            for (int k = 0; k < IT; ++k) {
                float e = fmaf(ax[k], q.x, fmaf(ay[k], q.y, fmaf(az[k], q.z, q.w)));
                m[k] = fminf(m[k], (j == idl[k]) ? 1e30f : e);
            }
        }
    } else {
#pragma unroll 8
        for (int j = 0; j < JG; j += 2) {      // paired -> v_min3
            float4 q0 = gp[j], q1 = gp[j+1];
#pragma unroll
            for (int k = 0; k < IT; ++k) {
                float e0 = fmaf(ax[k], q0.x, fmaf(ay[k], q0.y, fmaf(az[k], q0.z, q0.w)));
                float e1 = fmaf(ax[k], q1.x, fmaf(ay[k], q1.y, fmaf(az[k], q1.z, q1.w)));
                m[k] = fminf(fminf(m[k], e0), e1);
            }
        }
    }

    // ---- min across the wave's 4 groups (g = lane bits 4..5: xor 16, 32) ----
#pragma unroll
    for (int k = 0; k < IT; ++k) {
        m[k] = fminf(m[k], __shfl_xor(m[k], 16));
        m[k] = fminf(m[k], __shfl_xor(m[k], 32));
    }
    if (lane < QCOLS) {
#pragma unroll
        for (int k = 0; k < IT; ++k) smin[w][qcol * IT + k] = m[k];
    }
    __syncthreads();

    // ---- wave 0: min across 16 waves, exp, variance terms, block partials ----
    if (t < QPB) {
        float cx = 0.f, cy = 0.f, cz = 0.f;
#pragma unroll
        for (int ww = 0; ww < NW; ++ww) {
            cx += scen[ww][0]; cy += scen[ww][1]; cz += scen[ww][2];
        }
        cx *= (1.f / NPTS); cy *= (1.f / NPTS); cz *= (1.f / NPTS);

        float mm = smin[0][t];
#pragma unroll
        for (int ww = 1; ww < NW; ++ww) mm = fminf(mm, smin[ww][t]);

        int iq = iq0 + t;
        float4 q = lpt[PADIDX(iq)];
        float es = __expf(-5.f * fmaxf(q.w + mm, 0.f));   // clamp commutes with min

        float dx = q.x - cx, dy = q.y - cy, dz = q.z - cz;
        float d2 = fmaf(dx, dx, fmaf(dy, dy, dz * dz));
        float s1 = sqrtf(d2);

        es = wave_sum(es);
        float S1 = wave_sum(s1);
        float S2 = wave_sum(d2);
        if (t == 0) {
            bpart[blockIdx.x * 3 + 0] = S1;
            bpart[blockIdx.x * 3 + 1] = S2;
            bpart[blockIdx.x * 3 + 2] = es;
        }
    }
}

// wave w reduces batch w's 64 block-partials; lane0s combine via LDS.
__global__ __launch_bounds__(256) void finish_kernel(const float* __restrict__ bpart,
                                                     float* __restrict__ out) {
    __shared__ float svar[NB], ses[NB];
    int t = threadIdx.x;
    int w = t >> 6;                    // batch
    float s1 = bpart[t*3+0], s2 = bpart[t*3+1], es = bpart[t*3+2];
    s1 = wave_sum(s1); s2 = wave_sum(s2); es = wave_sum(es);
    if ((t & 63) == 0) {
        svar[w] = (s2 - s1 * s1 * (1.f / NPTS)) * (1.f / (NPTS - 1));
        ses[w]  = es;
    }
    __syncthreads();
    if (t == 0) {
        float vs = 0.f, et = 0.f;
#pragma unroll
        for (int bb = 0; bb < NB; ++bb) { vs += svar[bb]; et += ses[bb]; }
        out[0] = vs * (1.f / NB) + et * (1.f / BN);
    }
}

extern "C" void kernel_launch(void* const* d_in, const int* in_sizes, int n_in,
                              void* d_out, int out_size, void* d_ws, size_t ws_size,
                              hipStream_t stream) {
    const float* pc = (const float*)d_in[0];
    float* out   = (float*)d_out;
    float* bpart = (float*)d_ws;       // NBLK*3 floats = 3 KB

    fused_kernel<<<NBLK, TPB, 0, stream>>>(pc, bpart);
    finish_kernel<<<1, 256, 0, stream>>>(bpart, out);
}